// Round 7
// baseline (172.292 us; speedup 1.0000x reference)
//
#include <hip/hip_runtime.h>
#include <hip/hip_bf16.h>
#include <math.h>

// out[i,f] = tanh(b[f] + a[f] * dot(W[f,:], x[i,:]))
// GEMM M=32768 N=512 K=512, fp16 single-term MFMA (accuracy proven R6: 3.9e-3).
//
// Structure (latency-bound fix): persistent B-panel in LDS, zero K-loop barriers.
//  - Block = 512 thr (8 waves), owns 256 M-rows x 64 N-cols.
//  - Prologue: whole B panel (64 rows x 512 K fp16 = 64KB) -> LDS via
//    global_load_lds (1 row = 1KB = one wave-issue), pre-swizzled source
//    (slot sigma = (l&~7)|((l&7)^(r&7)), proven R5/R6), ONE barrier.
//  - K-loop: A fragments global->reg (two dwordx4 per frag, 16x128B coalesced
//    segments), distance-1 rotating prefetch with static names, convert to
//    fp16 in-reg, B frags via swizzled ds_read_b128 (0-conflict pattern),
//    8 MFMA/step. No barriers, no A-LDS -> waves free-run, TLP hides latency.
//  - XCD-bijective swizzle: vid=(bid&7)*128+(bid>>3); nPanel=vid&7, mChunk=vid>>3
//    -> each XCD sees 16 consecutive mChunks x all 8 panels (X slice ~L2-sized).

typedef _Float16     f16x8 __attribute__((ext_vector_type(8)));
typedef float        f32x4 __attribute__((ext_vector_type(4)));
typedef unsigned int u32x2 __attribute__((ext_vector_type(2)));
typedef unsigned int u32x4 __attribute__((ext_vector_type(4)));

static constexpr int Mdim = 32768;
static constexpr int Kdim = 512;
static constexpr int Ndim = 512;

__device__ __forceinline__ unsigned pk16(float a, float b) {
  union { _Float16 h; unsigned short u; } ca, cb;
  ca.h = (_Float16)a;  // v_cvt_f16_f32, RNE
  cb.h = (_Float16)b;
  return (unsigned)ca.u | ((unsigned)cb.u << 16);
}

__device__ __forceinline__ f16x8 pack8(f32x4 a, f32x4 b) {
  u32x4 u = { pk16(a[0], a[1]), pk16(a[2], a[3]), pk16(b[0], b[1]), pk16(b[2], b[3]) };
  union { u32x4 u; f16x8 h; } cv;
  cv.u = u;
  return cv.h;
}

__device__ __forceinline__ float fast_tanh(float x) {
  float e = __expf(2.0f * x);
  return 1.0f - 2.0f * __builtin_amdgcn_rcpf(e + 1.0f);
}

__device__ __forceinline__ void glds16(const unsigned short* g, unsigned short* l) {
  __builtin_amdgcn_global_load_lds(
      (const __attribute__((address_space(1))) unsigned int*)g,
      (__attribute__((address_space(3))) unsigned int*)l, 16, 0, 0);
}

// ---------------- pre-pass: W fp32 -> fp16 ----------------
__global__ __launch_bounds__(256) void conv_w(const float* __restrict__ Wm,
                                              unsigned short* __restrict__ wh) {
  const int idx = blockIdx.x * 256 + threadIdx.x;   // 65536 float4s
  f32x4 v = *(const f32x4*)(Wm + (size_t)idx * 4);
  u32x2 p = { pk16(v[0], v[1]), pk16(v[2], v[3]) };
  *(u32x2*)(wh + (size_t)idx * 4) = p;
}

// ---------------- main: persistent-B, barrier-free K loop ----------------
__global__ __launch_bounds__(512, 4) void gemm_bpanel(
    const float* __restrict__ X, const unsigned short* __restrict__ Wh,
    const float* __restrict__ avec, const float* __restrict__ bvec,
    float* __restrict__ out) {
  // B panel: 64 rows x 512 fp16 = 64 rows x 64 slots(16B) = 64KB.
  // Physical slot of logical slot s, row r: (s&~7) | ((s&7)^(r&7)).
  __shared__ unsigned short ldsB[64 * 512];

  const int bid = blockIdx.x;
  const int vid = (bid & 7) * 128 + (bid >> 3);  // XCD-contiguous, bijective
  const int nP  = vid & 7;    // N panel: 64 features
  const int mC  = vid >> 3;   // M chunk: 256 rows
  const int tid  = threadIdx.x;
  const int lane = tid & 63;
  const int wid  = tid >> 6;  // 8 waves; wave owns 32 rows x 64 cols

  // ---- prologue: stage B panel (one glds16 issue = one full row) ----
#pragma unroll
  for (int i = 0; i < 8; ++i) {
    const int r = wid * 8 + i;
    const int sigma = (lane & ~7) | ((lane & 7) ^ (r & 7));
    glds16(Wh + (size_t)(nP * 64 + r) * Kdim + sigma * 8, &ldsB[r * 512]);
  }
  __syncthreads();   // drains vmcnt; only barrier in the kernel

  const int p = lane & 15;       // fragment row within 16
  const int q = lane >> 4;       // k-subslot 0..3 (8 fp16 each)
  const int rowBase = mC * 256 + wid * 32;
  // A lane base: row (rowBase + mi*16 + p), cols t*32 + q*8 .. +8
  const float* Xl = X + (size_t)(rowBase + p) * Kdim + q * 8;

  f32x4 acc[2][4];
#pragma unroll
  for (int i = 0; i < 2; ++i)
#pragma unroll
    for (int j = 0; j < 4; ++j) acc[i][j] = {0.f, 0.f, 0.f, 0.f};

  // rotating distance-1 prefetch, static names (no runtime-indexed arrays)
  f32x4 n0 = *(const f32x4*)(Xl);
  f32x4 n1 = *(const f32x4*)(Xl + 4);
  f32x4 n2 = *(const f32x4*)(Xl + 16 * Kdim);
  f32x4 n3 = *(const f32x4*)(Xl + 16 * Kdim + 4);

#pragma unroll
  for (int t = 0; t < 16; ++t) {
    f32x4 c0 = n0, c1 = n1, c2 = n2, c3 = n3;
    if (t < 15) {
      const int kb = (t + 1) * 32;
      n0 = *(const f32x4*)(Xl + kb);
      n1 = *(const f32x4*)(Xl + kb + 4);
      n2 = *(const f32x4*)(Xl + 16 * Kdim + kb);
      n3 = *(const f32x4*)(Xl + 16 * Kdim + kb + 4);
    }
    f16x8 af0 = pack8(c0, c1);
    f16x8 af1 = pack8(c2, c3);

    const int s = 4 * t + q;             // logical slot (within 8-group: s&7)
#pragma unroll
    for (int ni = 0; ni < 4; ++ni) {
      const int r   = ni * 16 + p;       // r&7 == p&7
      const int off = r * 512 + ((s & ~7) | ((s & 7) ^ (p & 7))) * 8;
      f16x8 bf = *(const f16x8*)&ldsB[off];
      acc[0][ni] = __builtin_amdgcn_mfma_f32_16x16x32_f16(af0, bf, acc[0][ni], 0, 0, 0);
      acc[1][ni] = __builtin_amdgcn_mfma_f32_16x16x32_f16(af1, bf, acc[1][ni], 0, 0, 0);
    }
  }

  // Epilogue: C/D layout 16x16x32: col = lane&15 (feature), row = q*4 + reg.
  const int rq = q * 4;
#pragma unroll
  for (int ni = 0; ni < 4; ++ni) {
    const int gc = nP * 64 + ni * 16 + p;
    const float aa = avec[gc];
    const float bb = bvec[gc];
#pragma unroll
    for (int mi = 0; mi < 2; ++mi) {
      const int gr = rowBase + mi * 16 + rq;
      f32x4 v = acc[mi][ni];
#pragma unroll
      for (int j = 0; j < 4; ++j) {
        out[(size_t)(gr + j) * Ndim + gc] = fast_tanh(aa * v[j] + bb);
      }
    }
  }
}

// ------------- fallback (ws too small): bf16 3-term, proven ----------
typedef short bf16x8 __attribute__((ext_vector_type(8)));

__device__ __forceinline__ unsigned cvt_pk_bf16(float a, float b) {
  unsigned r;
  asm("v_cvt_pk_bf16_f32 %0, %1, %2" : "=v"(r) : "v"(a), "v"(b));
  return r;
}
__device__ __forceinline__ void split4(f32x4 v, u32x2& hi, u32x2& lo) {
  unsigned h0 = cvt_pk_bf16(v[0], v[1]);
  unsigned h1 = cvt_pk_bf16(v[2], v[3]);
  float f0 = __uint_as_float(h0 << 16);
  float f1 = __uint_as_float(h0 & 0xFFFF0000u);
  float f2 = __uint_as_float(h1 << 16);
  float f3 = __uint_as_float(h1 & 0xFFFF0000u);
  lo[0] = cvt_pk_bf16(v[0] - f0, v[1] - f1);
  lo[1] = cvt_pk_bf16(v[2] - f2, v[3] - f3);
  hi[0] = h0; hi[1] = h1;
}

__global__ __launch_bounds__(512, 4) void gemm_nows(
    const float* __restrict__ X, const float* __restrict__ Wm,
    const float* __restrict__ avec, const float* __restrict__ bvec,
    float* __restrict__ out) {
  __shared__ unsigned short lds[4][128 * 64];
  const int bid = blockIdx.x;
  const int nB  = bid & 3;
  const int mB  = bid >> 2;
  const int tid  = threadIdx.x;
  const int lane = tid & 63;
  const int wid  = tid >> 6;
  const int wm = wid >> 2, wn = wid & 3;

  f32x4 acc[4][2];
#pragma unroll
  for (int i = 0; i < 4; ++i)
#pragma unroll
    for (int j = 0; j < 2; ++j) acc[i][j] = {0.f, 0.f, 0.f, 0.f};

  const int srow  = tid >> 4;
  const int scol4 = tid & 15;
  const int kcol  = scol4 * 4;
  const int soff0 = kcol >> 3;
  const float* Xb = X  + (size_t)mB * 128 * Kdim;
  const float* Wb = Wm + (size_t)nB * 128 * Kdim;

  f32x4 rA[4], rB[4];
#pragma unroll
  for (int i = 0; i < 4; ++i) {
    const int row = srow + 32 * i;
    rA[i] = *(const f32x4*)(Xb + (size_t)row * Kdim + kcol);
    rB[i] = *(const f32x4*)(Wb + (size_t)row * Kdim + kcol);
  }
  for (int kt = 0; kt < Kdim / 64; ++kt) {
#pragma unroll
    for (int i = 0; i < 4; ++i) {
      const int row = srow + 32 * i;
      const int off = row * 64 + ((soff0 ^ (row & 7)) << 3) + (kcol & 7);
      u32x2 h, l;
      split4(rA[i], h, l);
      *(u32x2*)&lds[0][off] = h;
      *(u32x2*)&lds[1][off] = l;
      split4(rB[i], h, l);
      *(u32x2*)&lds[2][off] = h;
      *(u32x2*)&lds[3][off] = l;
    }
    __syncthreads();
    if (kt != Kdim / 64 - 1) {
      const int kbase = (kt + 1) * 64;
#pragma unroll
      for (int i = 0; i < 4; ++i) {
        const int row = srow + 32 * i;
        rA[i] = *(const f32x4*)(Xb + (size_t)row * Kdim + kbase + kcol);
        rB[i] = *(const f32x4*)(Wb + (size_t)row * Kdim + kbase + kcol);
      }
    }
#pragma unroll
    for (int ks = 0; ks < 2; ++ks) {
      const int slotBase = ks * 4 + (lane >> 4);
      bf16x8 bh[2], bl[2];
#pragma unroll
      for (int ni = 0; ni < 2; ++ni) {
        const int row = wn * 32 + ni * 16 + (lane & 15);
        const int off = row * 64 + ((slotBase ^ (row & 7)) << 3);
        bh[ni] = *(const bf16x8*)&lds[2][off];
        bl[ni] = *(const bf16x8*)&lds[3][off];
      }
#pragma unroll
      for (int mi = 0; mi < 4; ++mi) {
        const int row = wm * 64 + mi * 16 + (lane & 15);
        const int off = row * 64 + ((slotBase ^ (row & 7)) << 3);
        bf16x8 ah = *(const bf16x8*)&lds[0][off];
        bf16x8 al = *(const bf16x8*)&lds[1][off];
#pragma unroll
        for (int ni = 0; ni < 2; ++ni) {
          acc[mi][ni] = __builtin_amdgcn_mfma_f32_16x16x32_bf16(ah, bh[ni], acc[mi][ni], 0, 0, 0);
          acc[mi][ni] = __builtin_amdgcn_mfma_f32_16x16x32_bf16(ah, bl[ni], acc[mi][ni], 0, 0, 0);
          acc[mi][ni] = __builtin_amdgcn_mfma_f32_16x16x32_bf16(al, bh[ni], acc[mi][ni], 0, 0, 0);
        }
      }
    }
    __syncthreads();
  }
  const int c  = lane & 15;
  const int rq = (lane >> 4) * 4;
#pragma unroll
  for (int ni = 0; ni < 2; ++ni) {
    const int gc = nB * 128 + wn * 32 + ni * 16 + c;
    const float aa = avec[gc];
    const float bb = bvec[gc];
#pragma unroll
    for (int mi = 0; mi < 4; ++mi) {
      const int gr = mB * 128 + wm * 64 + mi * 16 + rq;
      f32x4 v = acc[mi][ni];
#pragma unroll
      for (int j = 0; j < 4; ++j) {
        out[(size_t)(gr + j) * Ndim + gc] = fast_tanh(aa * v[j] + bb);
      }
    }
  }
}

extern "C" void kernel_launch(void* const* d_in, const int* in_sizes, int n_in,
                              void* d_out, int out_size, void* d_ws, size_t ws_size,
                              hipStream_t stream) {
  const float* X  = (const float*)d_in[0];
  const float* Wm = (const float*)d_in[1];
  const float* av = (const float*)d_in[2];
  const float* bv = (const float*)d_in[3];
  float* out = (float*)d_out;

  const size_t wBytes = (size_t)Ndim * Kdim * sizeof(unsigned short); // 512 KB
  if (ws_size >= wBytes) {
    unsigned short* wh = (unsigned short*)d_ws;
    conv_w<<<dim3(Ndim * Kdim / 4 / 256), dim3(256), 0, stream>>>(Wm, wh);
    // grid: 128 mChunks x 8 nPanels = 1024 blocks (2 resident/CU)
    gemm_bpanel<<<dim3(1024), dim3(512), 0, stream>>>(X, wh, av, bv, out);
  } else {
    gemm_nows<<<dim3((Mdim / 128) * (Ndim / 128)), dim3(512), 0, stream>>>(X, Wm, av, bv, out);
  }
}